// Round 1
// baseline (644.354 us; speedup 1.0000x reference)
//
#include <hip/hip_runtime.h>
#include <math.h>

#define THREADS 192   // 3 waves; 192 rows = 64 batches per block (multiple of 3)
#define ROWS    192
#define PAD     65    // +1 pad: per-thread row reads hit banks (t+k)%32 -> 2-way (free)
#define CH      8     // m-chunk size

__global__ __launch_bounds__(THREADS, 1)
void edge_fused(const float* __restrict__ nodes,
                const float* __restrict__ W1,
                const float* __restrict__ b1,
                const float* __restrict__ W2,
                const float* __restrict__ b2,
                const float* __restrict__ ea,
                float* __restrict__ out)
{
    __shared__ float xl[ROWS * PAD];        // 49.9 KB: staged node rows
    __shared__ float vbuf[2][ROWS][CH];     // 12 KB: sibling v exchange (double-buffered)

    const int t = threadIdx.x;
    const size_t base = (size_t)blockIdx.x * (ROWS * 64);

    // ---- stage node rows into padded LDS (coalesced float4 reads) ----
    {
        const float4* src = (const float4*)(nodes + base);
        #pragma unroll
        for (int it = 0; it < (ROWS * 16) / THREADS; ++it) {
            int idx = t + it * THREADS;
            float4 val = src[idx];
            int row = idx >> 4;
            int k4  = (idx & 15) << 2;
            float* p = &xl[row * PAD + k4];
            p[0] = val.x; p[1] = val.y; p[2] = val.z; p[3] = val.w;
        }
    }

    // ---- per-thread softmax(edge_attn) row (i = node index of this row) ----
    const int i  = t % 3;
    const int bb = t - i;                 // first sibling row index in block
    float e0 = ea[i*3+0], e1 = ea[i*3+1], e2 = ea[i*3+2];
    float mx = fmaxf(e0, fmaxf(e1, e2));
    float a0 = expf(e0-mx), a1 = expf(e1-mx), a2 = expf(e2-mx);
    float inv = 1.0f / (a0 + a1 + a2);
    a0 *= inv; a1 *= inv; a2 *= inv;

    // layer-2 output accumulator (64 fp32 regs), init with bias
    float acc[64];
    #pragma unroll
    for (int d = 0; d < 64; ++d) acc[d] = b2[d];

    __syncthreads();

    const float* xrow = &xl[t * PAD];

    for (int mc = 0; mc < 64 / CH; ++mc) {
        const int m0 = mc * CH;
        float u[CH], v[CH];
        #pragma unroll
        for (int c = 0; c < CH; ++c) { u[c] = 0.f; v[c] = 0.f; }

        // u = x @ W1top chunk, v = x @ W1bot chunk.
        // k, m0, c are wave-uniform -> weight loads scalarize to s_load (SGPR operand FMA).
        #pragma unroll 8
        for (int k = 0; k < 64; ++k) {
            float x = xrow[k];
            const float* wt = &W1[k * 64 + m0];
            const float* wb = &W1[(k + 64) * 64 + m0];
            #pragma unroll
            for (int c = 0; c < CH; ++c) u[c] = fmaf(x, wt[c], u[c]);
            #pragma unroll
            for (int c = 0; c < CH; ++c) v[c] = fmaf(x, wb[c], v[c]);
        }

        // exchange v chunks between sibling rows of the same batch
        const int buf = mc & 1;
        #pragma unroll
        for (int c = 0; c < CH; ++c) vbuf[buf][t][c] = v[c];
        __syncthreads();

        // g = sum_j a_ij * gelu(u_i + v_j + b1)   (exact erf GELU)
        float g[CH];
        #pragma unroll
        for (int c = 0; c < CH; ++c) g[c] = 0.f;
        #pragma unroll
        for (int j = 0; j < 3; ++j) {
            const float aj = (j == 0) ? a0 : (j == 1) ? a1 : a2;
            #pragma unroll
            for (int c = 0; c < CH; ++c) {
                float s  = u[c] + vbuf[buf][bb + j][c] + b1[m0 + c];
                float ge = 0.5f * s * (1.0f + erff(s * 0.70710678118654752f));
                g[c] = fmaf(aj, ge, g[c]);
            }
        }

        // layer 2: acc[d] += g[m] * W2[m][d]  (W2 rows scalarized)
        #pragma unroll
        for (int c = 0; c < CH; ++c) {
            const float* w2r = &W2[(m0 + c) * 64];
            #pragma unroll
            for (int d = 0; d < 64; ++d)
                acc[d] = fmaf(g[c], w2r[d], acc[d]);
        }
    }

    __syncthreads();   // all xl reads done -> safe to reuse as output staging
    #pragma unroll
    for (int d = 0; d < 64; ++d) xl[t * PAD + d] = acc[d];
    __syncthreads();

    // ---- coalesced float4 store via LDS ----
    {
        float4* dst = (float4*)(out + base);
        #pragma unroll
        for (int it = 0; it < (ROWS * 16) / THREADS; ++it) {
            int idx = t + it * THREADS;
            int row = idx >> 4;
            int k4  = (idx & 15) << 2;
            const float* p = &xl[row * PAD + k4];
            dst[idx] = make_float4(p[0], p[1], p[2], p[3]);
        }
    }
}

extern "C" void kernel_launch(void* const* d_in, const int* in_sizes, int n_in,
                              void* d_out, int out_size, void* d_ws, size_t ws_size,
                              hipStream_t stream)
{
    const float* nodes = (const float*)d_in[0];
    const float* W1    = (const float*)d_in[1];
    const float* b1    = (const float*)d_in[2];
    const float* W2    = (const float*)d_in[3];
    const float* b2    = (const float*)d_in[4];
    const float* ea    = (const float*)d_in[5];
    float* out = (float*)d_out;

    const int total_rows = out_size / 64;     // B*3 = 786432
    const int grid = total_rows / ROWS;       // 4096
    edge_fused<<<grid, THREADS, 0, stream>>>(nodes, W1, b1, W2, b2, ea, out);
}